// Round 9
// baseline (470.909 us; speedup 1.0000x reference)
//
#include <hip/hip_runtime.h>
#include <stdint.h>

#define B_GRAPHS 256
#define NPER     512
#define EPER     4096
#define DDIM     64
#define KKEEP    1024
#define HIDDEN   256
#define JT       8
#define HTILES   16          // tiles per hidden-half block (16*8 = 128 hidden units)
#define STR      12          // LDS row stride (floats): 48B rows -> 16B aligned

// Kernel A: 512-thread blocks, TWO per graph (hb = hidden half).
// R6-R8 evidence: 1024-thread workgroups NEVER co-schedule (occupancy pinned
// ~47%), so their 3-barriers/tile serialize VALU and LDS phases with no other
// block to fill the bubbles. This version: thread t owns node n=t fully; its
// h-row is consumed in 16-float chunks re-read from L1/L2 each tile (asm
// memory clobber stops hoisting -> no 64-reg live set, no spill; R1/R3 trap).
// That removes the half-split reduction: 1 staging phase, 2 barriers/tile,
// and 48KB/8-wave blocks -> two co-resident per CU that overlap each other's
// barrier stalls. Swizzle b=bid&255, hb=bid>>8 keeps graph-halves on one XCD
// (R7 lesson: splitting them doubled the per-XCD footprint and pushed W1's
// scalar re-read stream out of L2).
__global__ __launch_bounds__(512) void scores_kernel(
    const float* __restrict__ h, const float* __restrict__ W1,
    const float* __restrict__ b1, const float* __restrict__ W2,
    const int* __restrict__ edge0, const int* __restrict__ edge1,
    float* __restrict__ sc_part)
{
  __shared__ __align__(16) float At[NPER * STR];   // 24 KB
  __shared__ __align__(16) float Bt[NPER * STR];   // 24 KB
  const int t   = threadIdx.x;
  const int bid = blockIdx.x;
  const int b   = bid & (B_GRAPHS - 1);   // graph
  const int hb  = bid >> 8;               // hidden half: units [hb*128, hb*128+128)
  const int n   = t;                      // this thread's node

  // 8 edges per thread, node ids packed
  int epk[8];
  float eacc[8];
#pragma unroll
  for (int i = 0; i < 8; ++i) {
    const size_t e = (size_t)b * EPER + t + i * 512;
    epk[i] = (edge0[e] & (NPER - 1)) | ((edge1[e] & (NPER - 1)) << 16);
    eacc[i] = 0.f;
  }

  const float* __restrict__ hrow = h + ((size_t)b * NPER + n) * DDIM;
  const float* __restrict__ W1b_ = W1 + (size_t)DDIM * HIDDEN;  // B rows 64..127

  for (int jt = 0; jt < HTILES; ++jt) {
    const int j0 = hb * (HTILES * JT) + jt * JT;

    // stop the compiler from hoisting the h chunk loads out of the tile loop
    asm volatile("" ::: "memory");

    float pa[JT], pb[JT];
#pragma unroll
    for (int jj = 0; jj < JT; ++jj) { pa[jj] = b1[j0 + jj]; pb[jj] = 0.f; }

#pragma unroll
    for (int dc = 0; dc < 4; ++dc) {
      // 16 floats of this node's h row (L1-resident after first touch)
      const float4* hp = (const float4*)(hrow + dc * 16);
      float4 h0 = hp[0], h1 = hp[1], h2 = hp[2], h3 = hp[3];
      float hc[16];
      hc[0]=h0.x; hc[1]=h0.y; hc[2]=h0.z; hc[3]=h0.w;
      hc[4]=h1.x; hc[5]=h1.y; hc[6]=h1.z; hc[7]=h1.w;
      hc[8]=h2.x; hc[9]=h2.y; hc[10]=h2.z; hc[11]=h2.w;
      hc[12]=h3.x; hc[13]=h3.y; hc[14]=h3.z; hc[15]=h3.w;
#pragma unroll
      for (int k = 0; k < 16; ++k) {
        const int d = dc * 16 + k;
        const float hv = hc[k];
#pragma unroll
        for (int jj = 0; jj < JT; ++jj)
          pa[jj] = fmaf(hv, W1[d * HIDDEN + j0 + jj], pa[jj]);   // uniform -> s_load
#pragma unroll
        for (int jj = 0; jj < JT; ++jj)
          pb[jj] = fmaf(hv, W1b_[d * HIDDEN + j0 + jj], pb[jj]);
      }
    }

    // stage this node's full A,B tile rows (single phase)
    {
      float4 s0 = {pa[0], pa[1], pa[2], pa[3]};
      float4 s1 = {pa[4], pa[5], pa[6], pa[7]};
      ((float4*)(At + n * STR))[0] = s0;
      ((float4*)(At + n * STR))[1] = s1;
      float4 u0 = {pb[0], pb[1], pb[2], pb[3]};
      float4 u1 = {pb[4], pb[5], pb[6], pb[7]};
      ((float4*)(Bt + n * STR))[0] = u0;
      ((float4*)(Bt + n * STR))[1] = u1;
    }
    __syncthreads();

    // edge gather over this tile
    float w2r[JT];
#pragma unroll
    for (int jj = 0; jj < JT; ++jj) w2r[jj] = W2[j0 + jj];   // uniform -> s_load

#pragma unroll
    for (int i = 0; i < 8; ++i) {
      const int er = epk[i] & 0xffff;
      const int ec = ((unsigned)epk[i]) >> 16;
      const float4* ar = (const float4*)(At + er * STR);
      const float4* br = (const float4*)(Bt + ec * STR);
      const float4 a0 = ar[0], a1 = ar[1];
      const float4 c0 = br[0], c1 = br[1];
      float p = 0.f;
      p = fmaf(fmaxf(a0.x + c0.x, 0.f), w2r[0], p);
      p = fmaf(fmaxf(a0.y + c0.y, 0.f), w2r[1], p);
      p = fmaf(fmaxf(a0.z + c0.z, 0.f), w2r[2], p);
      p = fmaf(fmaxf(a0.w + c0.w, 0.f), w2r[3], p);
      p = fmaf(fmaxf(a1.x + c1.x, 0.f), w2r[4], p);
      p = fmaf(fmaxf(a1.y + c1.y, 0.f), w2r[5], p);
      p = fmaf(fmaxf(a1.z + c1.z, 0.f), w2r[6], p);
      p = fmaf(fmaxf(a1.w + c1.w, 0.f), w2r[7], p);
      eacc[i] += p;
    }
    __syncthreads();   // tile consumed before next staging
  }

  // partial scores for this hidden half (b2 added at key build)
  float* out = sc_part + (size_t)hb * (B_GRAPHS * EPER) + (size_t)b * EPER;
#pragma unroll
  for (int i = 0; i < 8; ++i)
    out[t + i * 512] = eacc[i];
}

// Kernel B: per-graph bitonic sort of (score desc, idx asc) packed u64 keys;
// score = scA + scB + b2 summed at key build. Epilogue: edge weights, node
// mask, masked h-sum. (R1-verified structure.)
__global__ __launch_bounds__(1024) void sort_kernel(
    const float* __restrict__ scA, const float* __restrict__ scB,
    const float* __restrict__ b2, const int* __restrict__ edge0,
    const int* __restrict__ edge1, const float* __restrict__ h,
    float* __restrict__ out_rep, float* __restrict__ out_cw,
    float* __restrict__ out_sw)
{
  __shared__ unsigned long long keys[EPER];  // 32 KB
  __shared__ int mask[NPER];                 // 2 KB
  __shared__ float red[16 * 64];             // 4 KB
  const int t = threadIdx.x;
  const int b = blockIdx.x;
  const float b2v = b2[0];

  if (t < NPER) mask[t] = 0;

  // build keys: ascending u64 order == (score desc, edge idx asc)
#pragma unroll
  for (int i = 0; i < 4; ++i) {
    const int e = t + i * 1024;
    const float s = scA[(size_t)b * EPER + e] + scB[(size_t)b * EPER + e] + b2v;
    unsigned u  = __float_as_uint(s);
    unsigned fk = (u & 0x80000000u) ? ~u : (u | 0x80000000u);  // ascending-orderable
    unsigned dk = ~fk;                                          // descending
    keys[e] = ((unsigned long long)dk << 32) | (unsigned)e;
  }

  for (int k = 2; k <= EPER; k <<= 1) {
    for (int j = k >> 1; j > 0; j >>= 1) {
      __syncthreads();
#pragma unroll
      for (int i = 0; i < 4; ++i) {
        const int p = t + i * 1024;
        const int l = p ^ j;
        if (l > p) {
          const unsigned long long a = keys[p], c = keys[l];
          const bool up = ((p & k) == 0);
          if (up ? (a > c) : (a < c)) { keys[p] = c; keys[l] = a; }
        }
      }
    }
  }
  __syncthreads();

  // sorted outputs: positions [0,K) -> causal weights, [K,E) -> -score
#pragma unroll
  for (int i = 0; i < 4; ++i) {
    const int p = t + i * 1024;
    const unsigned long long key = keys[p];
    const unsigned fk = ~(unsigned)(key >> 32);
    const unsigned u  = (fk & 0x80000000u) ? (fk & 0x7fffffffu) : ~fk;  // exact bits back
    const float s = __uint_as_float(u);
    if (p < KKEEP) out_cw[(size_t)b * KKEEP + p] = s;
    else           out_sw[(size_t)b * (EPER - KKEEP) + (p - KKEEP)] = -s;
  }

  // node mask from kept edges (blockDim == KKEEP, so thread t owns position t)
  {
    const int e = (int)(keys[t] & 0xffffffffu);
    const size_t eg = (size_t)b * EPER + e;
    mask[edge0[eg] & (NPER - 1)] = 1;   // same-value LDS races are benign
    mask[edge1[eg] & (NPER - 1)] = 1;
  }
  __syncthreads();

  // masked segment sum: lanes = dims (coalesced h reads), 16 node-groups
  {
    const int d = t & 63, g = t >> 6;
    float s = 0.f;
    for (int nn = g; nn < NPER; nn += 16)
      if (mask[nn]) s += h[((size_t)b * NPER + nn) * DDIM + d];
    red[g * 64 + d] = s;
  }
  __syncthreads();
  if (t < 64) {
    float tot = 0.f;
#pragma unroll
    for (int g = 0; g < 16; ++g) tot += red[g * 64 + t];
    out_rep[(size_t)b * DDIM + t] = tot;
  }
}

extern "C" void kernel_launch(void* const* d_in, const int* in_sizes, int n_in,
                              void* d_out, int out_size, void* d_ws, size_t ws_size,
                              hipStream_t stream) {
  const float* h    = (const float*)d_in[0];
  const float* W1   = (const float*)d_in[1];
  const float* b1   = (const float*)d_in[2];
  const float* W2   = (const float*)d_in[3];
  const float* b2   = (const float*)d_in[4];
  const int*   eidx = (const int*)d_in[5];
  const int* edge0 = eidx;
  const int* edge1 = eidx + (size_t)B_GRAPHS * EPER;

  float* sc_part = (float*)d_ws;      // 2 x 4 MB partial-score scratch
  const float* scA = sc_part;
  const float* scB = sc_part + (size_t)B_GRAPHS * EPER;

  float* out     = (float*)d_out;
  float* out_rep = out;                                   // 256*64
  float* out_cw  = out + B_GRAPHS * DDIM;                 // 256*1024
  float* out_sw  = out_cw + (size_t)B_GRAPHS * KKEEP;     // 256*3072

  scores_kernel<<<B_GRAPHS * 2, 512, 0, stream>>>(h, W1, b1, W2, edge0, edge1, sc_part);
  sort_kernel<<<B_GRAPHS, 1024, 0, stream>>>(scA, scB, b2, edge0, edge1, h,
                                             out_rep, out_cw, out_sw);
}

// Round 10
// 335.412 us; speedup vs baseline: 1.4040x; 1.4040x over previous
//
#include <hip/hip_runtime.h>
#include <stdint.h>

#define B_GRAPHS 256
#define NPER     512
#define EPER     4096
#define DDIM     64
#define KKEEP    1024
#define HIDDEN   256
#define CT       16          // hidden columns per tile
#define NTILE    (HIDDEN/CT) // 16 tiles
#define STR      20          // LDS row stride: 16 cols + 4 pad = 80B, 16B-aligned

// Kernel A: one 1024-thread block per graph. Thread (n = t&511, ch = t>>9)
// computes the FULL dot-product (all 64 dims) for its 8 columns of the
// 16-column tile -- column-split means partials are disjoint: no cross-thread
// reduction, ONE staging phase, 2 barriers/tile x 16 tiles = 32 barriers
// (R6 had 96; post-mortem attributed ~400K of R6's 636K cyc/CU to barrier
// drains). h[n][.] is re-read from L1/L2 in 16-float chunks per tile; the asm
// clobber stops the compiler hoisting it into a 64-reg live set (R1/R3 trap:
// RA hard-caps 1024-thread kernels at 64 arch VGPRs and would spill).
// R6-R9 evidence: only ONE workgroup is ever resident per CU regardless of
// size/LDS, so single-block-per-graph with minimal barriers is the design.
__global__ __launch_bounds__(1024) void scores_kernel(
    const float* __restrict__ h, const float* __restrict__ W1,
    const float* __restrict__ b1, const float* __restrict__ W2,
    const float* __restrict__ b2, const int* __restrict__ edge0,
    const int* __restrict__ edge1, float* __restrict__ sc_out)
{
  __shared__ __align__(16) float At[NPER * STR];   // 40 KB
  __shared__ __align__(16) float Bt[NPER * STR];   // 40 KB
  const int t  = threadIdx.x;
  const int b  = blockIdx.x;
  const int n  = t & (NPER - 1);
  const int ch = __builtin_amdgcn_readfirstlane(t >> 9);  // column half (wave-uniform)

  // 4 edges per thread, node ids packed
  int epk[4];
  float eacc[4];
#pragma unroll
  for (int i = 0; i < 4; ++i) {
    const size_t e = (size_t)b * EPER + t + i * 1024;
    epk[i] = (edge0[e] & (NPER - 1)) | ((edge1[e] & (NPER - 1)) << 16);
    eacc[i] = 0.f;
  }

  const float* __restrict__ hrow = h + ((size_t)b * NPER + n) * DDIM;

  for (int jt = 0; jt < NTILE; ++jt) {
    const int j0 = jt * CT;            // tile's first column
    const int jc = j0 + ch * 8;        // this thread's 8 columns (wave-uniform)

    asm volatile("" ::: "memory");     // no hoisting of h loads across tiles

    float pa[8], pb[8];
#pragma unroll
    for (int jj = 0; jj < 8; ++jj) { pa[jj] = b1[jc + jj]; pb[jj] = 0.f; }

#pragma unroll
    for (int dc = 0; dc < 4; ++dc) {
      const float4* hp = (const float4*)(hrow + dc * 16);
      float4 h0 = hp[0], h1 = hp[1], h2 = hp[2], h3 = hp[3];
      float hc[16];
      hc[0]=h0.x; hc[1]=h0.y; hc[2]=h0.z; hc[3]=h0.w;
      hc[4]=h1.x; hc[5]=h1.y; hc[6]=h1.z; hc[7]=h1.w;
      hc[8]=h2.x; hc[9]=h2.y; hc[10]=h2.z; hc[11]=h2.w;
      hc[12]=h3.x; hc[13]=h3.y; hc[14]=h3.z; hc[15]=h3.w;
#pragma unroll
      for (int k = 0; k < 16; ++k) {
        const int d = dc * 16 + k;
        const float hv = hc[k];
#pragma unroll
        for (int jj = 0; jj < 8; ++jj)
          pa[jj] = fmaf(hv, W1[d * HIDDEN + jc + jj], pa[jj]);          // s_loads
#pragma unroll
        for (int jj = 0; jj < 8; ++jj)
          pb[jj] = fmaf(hv, W1[(DDIM + d) * HIDDEN + jc + jj], pb[jj]); // s_loads
      }
    }

    // stage: disjoint 8-col halves of the 16-col row (single phase)
    {
      float* ap = At + n * STR + ch * 8;
      float* bp = Bt + n * STR + ch * 8;
      float4 s0 = {pa[0], pa[1], pa[2], pa[3]};
      float4 s1 = {pa[4], pa[5], pa[6], pa[7]};
      ((float4*)ap)[0] = s0; ((float4*)ap)[1] = s1;
      float4 u0 = {pb[0], pb[1], pb[2], pb[3]};
      float4 u1 = {pb[4], pb[5], pb[6], pb[7]};
      ((float4*)bp)[0] = u0; ((float4*)bp)[1] = u1;
    }
    __syncthreads();

    // edge gather over the 16-col tile
    float w2r[CT];
#pragma unroll
    for (int jj = 0; jj < CT; ++jj) w2r[jj] = W2[j0 + jj];   // uniform -> s_load

#pragma unroll
    for (int i = 0; i < 4; ++i) {
      const int er = epk[i] & 0xffff;
      const int ec = ((unsigned)epk[i]) >> 16;
      const float4* ar = (const float4*)(At + er * STR);
      const float4* br = (const float4*)(Bt + ec * STR);
      float p = 0.f;
#pragma unroll
      for (int q = 0; q < 4; ++q) {
        const float4 a = ar[q], c = br[q];
        p = fmaf(fmaxf(a.x + c.x, 0.f), w2r[4*q+0], p);
        p = fmaf(fmaxf(a.y + c.y, 0.f), w2r[4*q+1], p);
        p = fmaf(fmaxf(a.z + c.z, 0.f), w2r[4*q+2], p);
        p = fmaf(fmaxf(a.w + c.w, 0.f), w2r[4*q+3], p);
      }
      eacc[i] += p;
    }
    __syncthreads();   // tile consumed before next staging
  }

  const float b2v = b2[0];
#pragma unroll
  for (int i = 0; i < 4; ++i)
    sc_out[(size_t)b * EPER + t + i * 1024] = eacc[i] + b2v;
}

// Kernel B: per-graph bitonic sort of (score desc, idx asc) packed u64 keys,
// write causal/spurious edge weights, build node mask from kept edges,
// masked-sum h -> causal_rep. One block per graph.  (R1-verified version.)
__global__ __launch_bounds__(1024) void sort_kernel(
    const float* __restrict__ sc, const int* __restrict__ edge0,
    const int* __restrict__ edge1, const float* __restrict__ h,
    float* __restrict__ out_rep, float* __restrict__ out_cw,
    float* __restrict__ out_sw)
{
  __shared__ unsigned long long keys[EPER];  // 32 KB
  __shared__ int mask[NPER];                 // 2 KB
  __shared__ float red[16 * 64];             // 4 KB
  const int t = threadIdx.x;
  const int b = blockIdx.x;

  if (t < NPER) mask[t] = 0;

  // build keys: ascending u64 order == (score desc, edge idx asc)
#pragma unroll
  for (int i = 0; i < 4; ++i) {
    const int e = t + i * 1024;
    const float s = sc[(size_t)b * EPER + e];
    unsigned u  = __float_as_uint(s);
    unsigned fk = (u & 0x80000000u) ? ~u : (u | 0x80000000u);  // ascending-orderable
    unsigned dk = ~fk;                                          // descending
    keys[e] = ((unsigned long long)dk << 32) | (unsigned)e;
  }

  for (int k = 2; k <= EPER; k <<= 1) {
    for (int j = k >> 1; j > 0; j >>= 1) {
      __syncthreads();
#pragma unroll
      for (int i = 0; i < 4; ++i) {
        const int p = t + i * 1024;
        const int l = p ^ j;
        if (l > p) {
          const unsigned long long a = keys[p], c = keys[l];
          const bool up = ((p & k) == 0);
          if (up ? (a > c) : (a < c)) { keys[p] = c; keys[l] = a; }
        }
      }
    }
  }
  __syncthreads();

  // sorted outputs: positions [0,K) -> causal weights, [K,E) -> -score
#pragma unroll
  for (int i = 0; i < 4; ++i) {
    const int p = t + i * 1024;
    const unsigned long long key = keys[p];
    const unsigned fk = ~(unsigned)(key >> 32);
    const unsigned u  = (fk & 0x80000000u) ? (fk & 0x7fffffffu) : ~fk;  // exact bits back
    const float s = __uint_as_float(u);
    if (p < KKEEP) out_cw[(size_t)b * KKEEP + p] = s;
    else           out_sw[(size_t)b * (EPER - KKEEP) + (p - KKEEP)] = -s;
  }

  // node mask from kept edges (blockDim == KKEEP, so thread t owns position t)
  {
    const int e = (int)(keys[t] & 0xffffffffu);
    const size_t eg = (size_t)b * EPER + e;
    mask[edge0[eg] & (NPER - 1)] = 1;   // same-value LDS races are benign
    mask[edge1[eg] & (NPER - 1)] = 1;
  }
  __syncthreads();

  // masked segment sum: lanes = dims (coalesced h reads), 16 node-groups
  {
    const int d = t & 63, g = t >> 6;
    float s = 0.f;
    for (int nn = g; nn < NPER; nn += 16)
      if (mask[nn]) s += h[((size_t)b * NPER + nn) * DDIM + d];
    red[g * 64 + d] = s;
  }
  __syncthreads();
  if (t < 64) {
    float tot = 0.f;
#pragma unroll
    for (int g = 0; g < 16; ++g) tot += red[g * 64 + t];
    out_rep[(size_t)b * DDIM + t] = tot;
  }
}

extern "C" void kernel_launch(void* const* d_in, const int* in_sizes, int n_in,
                              void* d_out, int out_size, void* d_ws, size_t ws_size,
                              hipStream_t stream) {
  const float* h    = (const float*)d_in[0];
  const float* W1   = (const float*)d_in[1];
  const float* b1   = (const float*)d_in[2];
  const float* W2   = (const float*)d_in[3];
  const float* b2   = (const float*)d_in[4];
  const int*   eidx = (const int*)d_in[5];
  const int* edge0 = eidx;
  const int* edge1 = eidx + (size_t)B_GRAPHS * EPER;

  float* sc = (float*)d_ws;                 // 4 MB scratch for scores

  float* out     = (float*)d_out;
  float* out_rep = out;                                   // 256*64
  float* out_cw  = out + B_GRAPHS * DDIM;                 // 256*1024
  float* out_sw  = out_cw + (size_t)B_GRAPHS * KKEEP;     // 256*3072

  scores_kernel<<<B_GRAPHS, 1024, 0, stream>>>(h, W1, b1, W2, b2, edge0, edge1, sc);
  sort_kernel<<<B_GRAPHS, 1024, 0, stream>>>(sc, edge0, edge1, h, out_rep, out_cw, out_sw);
}